// Round 3
// baseline (1446.247 us; speedup 1.0000x reference)
//
#include <hip/hip_runtime.h>
#include <hip/hip_bf16.h>

#define T_STEPS 1024
#define B_SEQ   4096

// row_ror:N within 16-lane rows: dst[i] = src[(i-N)&15]  (same direction as the
// row_shr scan idiom; encoding 0x120+N per DPP_CTRL enum).
#define ROR(x, N) __int_as_float(__builtin_amdgcn_mov_dpp(__float_as_int(x), 0x120 + (N), 0xF, 0xF, false))

__device__ __forceinline__ float tanh_fast(float x) {
    // tanh(x) = 1 - 2/(e^{2x}+1), clamped to +-20 (saturates exactly in f32)
    float xc = fminf(fmaxf(x, -20.0f), 20.0f);
    float e  = __builtin_amdgcn_exp2f(xc * 2.88539008177793f); // 2^(2x*log2 e)
    return fmaf(-2.0f, __builtin_amdgcn_rcpf(e + 1.0f), 1.0f);
}

// Runtime dtype sniff: interpret first 64 elements as bf16. f32 data puts
// near-uniform mantissa bits in even slots -> absurd bf16 values with ~82%
// probability each; all-plausible => genuinely bf16. P(false verdict) ~ 1e-24.
__device__ __forceinline__ bool sniff_is_bf16(const void* p) {
    unsigned short h = ((const unsigned short*)p)[threadIdx.x & 63];
    union { unsigned u; float f; } c; c.u = ((unsigned)h) << 16;
    float f = fabsf(c.f);
    bool bad = !(f <= 1e4f) || (f != 0.0f && f < 1e-10f);
    return __ballot(bad) == 0ULL;
}

__device__ __forceinline__ float ldf(const void* p, long long i, bool isbf) {
    if (isbf) {
        unsigned short h = ((const unsigned short*)p)[i];
        union { unsigned u; float f; } c; c.u = ((unsigned)h) << 16;
        return c.f;
    }
    return ((const float*)p)[i];
}

// 64-thread (single-wave) blocks; 2 sequences per block.
// lane = seq_local*32 + net*16 + j   (net 0 -> r1 MLP, net 1 -> r2 MLP)
__global__ __launch_bounds__(64, 2) void reac_rk4_kernel(
    const void* __restrict__ u_,     const void* __restrict__ xz0_,
    const void* __restrict__ r1_W0_, const void* __restrict__ r1_b0_,
    const void* __restrict__ r1_W1_, const void* __restrict__ r1_b1_,
    const void* __restrict__ r1_W2_, const void* __restrict__ r1_b2_,
    const void* __restrict__ r2_W0_, const void* __restrict__ r2_b0_,
    const void* __restrict__ r2_W1_, const void* __restrict__ r2_b1_,
    const void* __restrict__ r2_W2_, const void* __restrict__ r2_b2_,
    const void* __restrict__ ymean_, const void* __restrict__ ystd_,
    const void* __restrict__ umean_, const void* __restrict__ ustd_,
    float* __restrict__ out)
{
    const int tid = threadIdx.x;            // 0..63
    const int j   = tid & 15;               // hidden unit
    const int net = (tid >> 4) & 1;         // 0 = r1, 1 = r2
    const long long b = (long long)blockIdx.x * 2 + (tid >> 5);

    const bool vW = sniff_is_bf16(r1_W1_);  // verdict for all weight/stat arrays
    const bool vU = sniff_is_bf16(u_);
    const bool vX = sniff_is_bf16(xz0_);

    // ---- per-lane weights (f32, loaded once) ----
    float w0a, w0b, b0;
    if (net) { w0a = ldf(r2_W0_, j, vW); w0b = ldf(r2_W0_, 16 + j, vW); b0 = ldf(r2_b0_, j, vW); }
    else     { w0a = ldf(r1_W0_, j, vW); w0b = 0.0f;                    b0 = ldf(r1_b0_, j, vW); }
    // DPP-rotation-ordered W1 column j: wr[m] = W1[(j-m)&15][j]
    float wr[16];
    {
        const void* W1 = net ? r2_W1_ : r1_W1_;
        #pragma unroll
        for (int m = 0; m < 16; ++m) wr[m] = ldf(W1, ((j - m) & 15) * 16 + j, vW);
    }
    const float b1v = ldf(net ? r2_b1_ : r1_b1_, j, vW);
    const float w2v = ldf(net ? r2_W2_ : r1_W2_, j, vW);
    const float b2v = ldf(net ? r2_b2_ : r1_b2_, 0, vW);

    const float Camean = ldf(ymean_, 0, vW), Cbmean = ldf(ymean_, 1, vW);
    const float Castd  = ldf(ystd_,  0, vW), Cbstd  = ldf(ystd_,  1, vW);
    const float um     = ldf(umean_, 0, vW), us     = ldf(ustd_,  0, vW);
    const float invCastd = 1.0f / Castd, invCbstd = 1.0f / Cbstd;

    // ---- state (replicated across the sequence's 32 lanes) ----
    float Ca = ldf(xz0_, b * 3 + 0, vX);
    float Cb = ldf(xz0_, b * 3 + 1, vX);
    float Cc = ldf(xz0_, b * 3 + 2, vX);

    // ---- output lane roles: c=0,1 -> yseq; c=2,3,4 -> xseq ----
    const int  c      = tid & 31;
    const bool active = (c < 5);
    float* sp;
    int sstr;
    if (c < 2) { sp = out + b * (T_STEPS * 2) + c;                                        sstr = 2; }
    else       { sp = out + (long long)B_SEQ * T_STEPS * 2 + b * (T_STEPS * 3) + (c - 2); sstr = 3; }
    const bool selA = (c == 0) | (c == 2);
    const bool selB = (c == 1) | (c == 3);

    const long long ubase = b * T_STEPS;
    float ut = ldf(u_, ubase, vU);

    auto fxu = [&](float xa, float xb, float xc, float fCaf,
                   float& ka, float& kb, float& kc) {
        // layer 1
        float A0   = net ? xb : xa;
        float pre1 = fmaf(w0a, A0, fmaf(w0b, xc, b0));
        float h1   = tanh_fast(pre1);
        // layer 2: 16-dot via DPP row rotations, 4 independent FMA chains
        float a0 = fmaf(h1, wr[0], b1v);
        float a1 = ROR(h1, 1)  * wr[1];
        float a2 = ROR(h1, 2)  * wr[2];
        float a3 = ROR(h1, 3)  * wr[3];
        a0 = fmaf(ROR(h1, 4),  wr[4],  a0);
        a1 = fmaf(ROR(h1, 5),  wr[5],  a1);
        a2 = fmaf(ROR(h1, 6),  wr[6],  a2);
        a3 = fmaf(ROR(h1, 7),  wr[7],  a3);
        a0 = fmaf(ROR(h1, 8),  wr[8],  a0);
        a1 = fmaf(ROR(h1, 9),  wr[9],  a1);
        a2 = fmaf(ROR(h1, 10), wr[10], a2);
        a3 = fmaf(ROR(h1, 11), wr[11], a3);
        a0 = fmaf(ROR(h1, 12), wr[12], a0);
        a1 = fmaf(ROR(h1, 13), wr[13], a1);
        a2 = fmaf(ROR(h1, 14), wr[14], a2);
        a3 = fmaf(ROR(h1, 15), wr[15], a3);
        float h2 = tanh_fast((a0 + a1) + (a2 + a3));
        // layer 3: cyclic rotate-reduce over the 16-lane row
        float p = h2 * w2v;
        p += ROR(p, 8); p += ROR(p, 4); p += ROR(p, 2); p += ROR(p, 1);
        float ov = p + b2v;
        // exchange r1 <-> r2 (xor 16 within each 32-lane half)
        float other = __int_as_float(__builtin_amdgcn_ds_swizzle(__float_as_int(ov), 0x401F));
        float r1v = (net ? other : ov) * Castd;
        float r2v = (net ? ov : other) * Cbstd;
        // physics (replicated, cheap)
        float Ca_p = fmaf(xa, Castd, Camean);
        float Cb_p = fmaf(xb, Cbstd, Cbmean);
        float Cc_p = fmaf(xc, Cbstd, Cbmean);
        float dCa  = fmaf(-0.1f, Ca_p, fCaf) - r1v;
        float dCb  = fmaf(-0.1f, Cb_p, fmaf(-3.0f, r2v, r1v));
        float dCc  = fmaf(-0.1f, Cc_p, r2v);
        ka = dCa * invCastd; kb = dCb * invCbstd; kc = dCc * invCbstd;
    };

    for (int t = 0; t < T_STEPS; ++t) {
        // scan emits the pre-update state
        float v = selA ? Ca : (selB ? Cb : Cc);
        if (active) { *sp = v; sp += sstr; }
        if (t == T_STEPS - 1) break;

        float utn  = ldf(u_, ubase + t + 1, vU);   // prefetch next u
        float fCaf = 0.1f * fmaf(ut, us, um);      // 0.1 * Caf_p

        float k1a, k1b, k1c, k2a, k2b, k2c, k3a, k3b, k3c, k4a, k4b, k4c;
        fxu(Ca, Cb, Cc, fCaf, k1a, k1b, k1c);
        fxu(fmaf(0.5f, k1a, Ca), fmaf(0.5f, k1b, Cb), fmaf(0.5f, k1c, Cc), fCaf, k2a, k2b, k2c);
        fxu(fmaf(0.5f, k2a, Ca), fmaf(0.5f, k2b, Cb), fmaf(0.5f, k2c, Cc), fCaf, k3a, k3b, k3c);
        fxu(Ca + k3a, Cb + k3b, Cc + k3c, fCaf, k4a, k4b, k4c);

        float sa = k1a + 2.0f * (k2a + k3a) + k4a;
        float sb = k1b + 2.0f * (k2b + k3b) + k4b;
        float sc = k1c + 2.0f * (k2c + k3c) + k4c;
        const float sixth = 1.0f / 6.0f;
        Ca = fmaf(sixth, sa, Ca);
        Cb = fmaf(sixth, sb, Cb);
        Cc = fmaf(sixth, sc, Cc);
        ut = utn;
    }
}

extern "C" void kernel_launch(void* const* d_in, const int* in_sizes, int n_in,
                              void* d_out, int out_size, void* d_ws, size_t ws_size,
                              hipStream_t stream) {
    (void)in_sizes; (void)n_in; (void)out_size; (void)d_ws; (void)ws_size;
    dim3 grid(B_SEQ / 2);   // 2048 single-wave blocks
    dim3 block(64);
    reac_rk4_kernel<<<grid, block, 0, stream>>>(
        d_in[0],  d_in[1],
        d_in[2],  d_in[3],  d_in[4],  d_in[5],  d_in[6],  d_in[7],
        d_in[8],  d_in[9],  d_in[10], d_in[11], d_in[12], d_in[13],
        d_in[14], d_in[15], d_in[16], d_in[17],
        (float*)d_out);
}

// Round 4
// 1233.259 us; speedup vs baseline: 1.1727x; 1.1727x over previous
//
#include <hip/hip_runtime.h>

#define T_STEPS 1024
#define B_SEQ   4096

typedef float v2f __attribute__((ext_vector_type(2)));

// DPP row_ror:N within 16-lane rows: dst[i] = src[(i-N)&15]
#define ROR(x, N) __int_as_float(__builtin_amdgcn_mov_dpp(__float_as_int(x), 0x120 + (N), 0xF, 0xF, false))
// ds_swizzle BitMode: lane' = lane ^ m (and=0x1F, or=0, xor=m) -> offset (m<<10)|0x1F
#define SWZ(x, IMM) __int_as_float(__builtin_amdgcn_ds_swizzle(__float_as_int(x), IMM))

__device__ __forceinline__ v2f pkfma(v2f a, v2f b, v2f c) {
    return __builtin_elementwise_fma(a, b, c);
}

// tanh(x) = 1 - 2/(e^{2x}+1). No clamp needed: exp2 overflow -> inf -> rcp -> 0
// -> +1 exact; underflow -> 0 -> rcp(1)=1 -> -1 exact.
__device__ __forceinline__ float tanh_fast(float x) {
    float e = __builtin_amdgcn_exp2f(x * 2.88539008177793f);
    return fmaf(-2.0f, __builtin_amdgcn_rcpf(e + 1.0f), 1.0f);
}

// Runtime dtype sniff (insurance; round-1/2 evidence says inputs are f32).
__device__ __forceinline__ bool sniff_is_bf16(const void* p) {
    unsigned short h = ((const unsigned short*)p)[threadIdx.x & 63];
    union { unsigned u; float f; } c; c.u = ((unsigned)h) << 16;
    float f = fabsf(c.f);
    bool bad = !(f <= 1e4f) || (f != 0.0f && f < 1e-10f);
    return __ballot(bad) == 0ULL;
}

__device__ __forceinline__ float ldf(const void* p, long long i, bool isbf) {
    if (isbf) {
        unsigned short h = ((const unsigned short*)p)[i];
        union { unsigned u; float f; } c; c.u = ((unsigned)h) << 16;
        return c.f;
    }
    return ((const float*)p)[i];
}

// 64-thread single-wave blocks; 2 sequences per block.
// lane = seq_local*32 + net*16 + j
__global__ __launch_bounds__(64, 2) void reac_rk4_kernel(
    const void* __restrict__ u_,     const void* __restrict__ xz0_,
    const void* __restrict__ r1_W0_, const void* __restrict__ r1_b0_,
    const void* __restrict__ r1_W1_, const void* __restrict__ r1_b1_,
    const void* __restrict__ r1_W2_, const void* __restrict__ r1_b2_,
    const void* __restrict__ r2_W0_, const void* __restrict__ r2_b0_,
    const void* __restrict__ r2_W1_, const void* __restrict__ r2_b1_,
    const void* __restrict__ r2_W2_, const void* __restrict__ r2_b2_,
    const void* __restrict__ ymean_, const void* __restrict__ ystd_,
    const void* __restrict__ umean_, const void* __restrict__ ustd_,
    float* __restrict__ out)
{
    const int tid = threadIdx.x;
    const int j   = tid & 15;
    const int net = (tid >> 4) & 1;
    const long long b = (long long)blockIdx.x * 2 + (tid >> 5);

    const bool vW = sniff_is_bf16(r1_W1_);
    const bool vU = sniff_is_bf16(u_);
    const bool vX = sniff_is_bf16(xz0_);

    // ---- per-lane weights ----
    float w0a, w0b, b0;
    if (net) { w0a = ldf(r2_W0_, j, vW); w0b = ldf(r2_W0_, 16 + j, vW); b0 = ldf(r2_b0_, j, vW); }
    else     { w0a = ldf(r1_W0_, j, vW); w0b = 0.0f;                    b0 = ldf(r1_b0_, j, vW); }

    const void* W1 = net ? r2_W1_ : r1_W1_;
    // ROR-ordered pairs: wr[t] = { W1[(j-2t)&15][j], W1[(j-2t-1)&15][j] }
    v2f wr[8];
    #pragma unroll
    for (int t = 0; t < 8; ++t) {
        wr[t].x = ldf(W1, ((j - 2 * t)     & 15) * 16 + j, vW);
        wr[t].y = ldf(W1, ((j - 2 * t - 1) & 15) * 16 + j, vW);
    }
    // XOR-ordered pairs: wx[t] = { W1[j^(2t)][j], W1[j^(2t+1)][j] }
    v2f wx[8];
    #pragma unroll
    for (int t = 0; t < 8; ++t) {
        wx[t].x = ldf(W1, ((j ^ (2 * t))     & 15) * 16 + j, vW);
        wx[t].y = ldf(W1, ((j ^ (2 * t + 1)) & 15) * 16 + j, vW);
    }
    const float b1v = ldf(net ? r2_b1_ : r1_b1_, j, vW);

    const float Camean = ldf(ymean_, 0, vW), Cbmean = ldf(ymean_, 1, vW);
    const float Castd  = ldf(ystd_,  0, vW), Cbstd  = ldf(ystd_,  1, vW);
    const float um     = ldf(umean_, 0, vW), us     = ldf(ustd_,  0, vW);
    const float invCastd = 1.0f / Castd, invCbstd = 1.0f / Cbstd;

    // fold output std into layer-3 weights: r1v/r2v come out pre-scaled
    const float ostd = net ? Cbstd : Castd;
    const float w2s  = ldf(net ? r2_W2_ : r1_W2_, j, vW) * ostd;
    const float b2s  = ldf(net ? r2_b2_ : r1_b2_, 0, vW) * ostd;

    // ---- state: (Ca,Cb) packed + Cc scalar, replicated over the 32 lanes ----
    v2f   Cab = { ldf(xz0_, b * 3 + 0, vX), ldf(xz0_, b * 3 + 1, vX) };
    float Cc  =   ldf(xz0_, b * 3 + 2, vX);

    // ---- output lanes: c=0,1 -> yseq; c=2,3,4 -> xseq ----
    const int  c      = tid & 31;
    const bool active = (c < 5);
    float* sp;
    int sstr;
    if (c < 2) { sp = out + b * (T_STEPS * 2) + c;                                        sstr = 2; }
    else       { sp = out + (long long)B_SEQ * T_STEPS * 2 + b * (T_STEPS * 3) + (c - 2); sstr = 3; }
    const bool selA = (c == 0) | (c == 2);
    const bool selB = (c == 1) | (c == 3);

    const long long ubase = b * T_STEPS;
    float ut = ldf(u_, ubase, vU);

    const v2f HALF2  = { 0.5f, 0.5f };
    const v2f TWO2   = { 2.0f, 2.0f };
    const v2f SIXTH2 = { 1.0f / 6.0f, 1.0f / 6.0f };
    const v2f STD2   = { Castd, Cbstd };
    const v2f MEAN2  = { Camean, Cbmean };
    const v2f ISTD2  = { invCastd, invCbstd };

    // One RK4 stage. UseXor selects the all-to-all transport:
    // false -> DPP row_ror (VALU pipe), true -> ds_swizzle xor (LDS pipe).
    auto fxu = [&](auto use_xor, v2f xab, float xc, float fCaf,
                   v2f& kab, float& kc) {
        constexpr bool UX = decltype(use_xor)::value;
        float A0 = net ? xab.y : xab.x;
        float h1 = tanh_fast(fmaf(w0a, A0, fmaf(w0b, xc, b0)));

        v2f acc0 = { b1v, 0.0f }, acc1 = { 0.0f, 0.0f };
        v2f h;
        if constexpr (UX) {
            h.x = h1;              h.y = SWZ(h1, 0x041F); acc0 = pkfma(h, wx[0], acc0);
            h.x = SWZ(h1, 0x081F); h.y = SWZ(h1, 0x0C1F); acc1 = pkfma(h, wx[1], acc1);
            h.x = SWZ(h1, 0x101F); h.y = SWZ(h1, 0x141F); acc0 = pkfma(h, wx[2], acc0);
            h.x = SWZ(h1, 0x181F); h.y = SWZ(h1, 0x1C1F); acc1 = pkfma(h, wx[3], acc1);
            h.x = SWZ(h1, 0x201F); h.y = SWZ(h1, 0x241F); acc0 = pkfma(h, wx[4], acc0);
            h.x = SWZ(h1, 0x281F); h.y = SWZ(h1, 0x2C1F); acc1 = pkfma(h, wx[5], acc1);
            h.x = SWZ(h1, 0x301F); h.y = SWZ(h1, 0x341F); acc0 = pkfma(h, wx[6], acc0);
            h.x = SWZ(h1, 0x381F); h.y = SWZ(h1, 0x3C1F); acc1 = pkfma(h, wx[7], acc1);
        } else {
            h.x = h1;          h.y = ROR(h1, 1);  acc0 = pkfma(h, wr[0], acc0);
            h.x = ROR(h1, 2);  h.y = ROR(h1, 3);  acc1 = pkfma(h, wr[1], acc1);
            h.x = ROR(h1, 4);  h.y = ROR(h1, 5);  acc0 = pkfma(h, wr[2], acc0);
            h.x = ROR(h1, 6);  h.y = ROR(h1, 7);  acc1 = pkfma(h, wr[3], acc1);
            h.x = ROR(h1, 8);  h.y = ROR(h1, 9);  acc0 = pkfma(h, wr[4], acc0);
            h.x = ROR(h1, 10); h.y = ROR(h1, 11); acc1 = pkfma(h, wr[5], acc1);
            h.x = ROR(h1, 12); h.y = ROR(h1, 13); acc0 = pkfma(h, wr[6], acc0);
            h.x = ROR(h1, 14); h.y = ROR(h1, 15); acc1 = pkfma(h, wr[7], acc1);
        }
        v2f accs = acc0 + acc1;                       // pk_add
        float h2 = tanh_fast(accs.x + accs.y);

        // layer 3: rotate-reduce over the 16-lane net group (pre-scaled by ostd)
        float p = h2 * w2s;
        p += ROR(p, 8); p += ROR(p, 4); p += ROR(p, 2); p += ROR(p, 1);
        float ov    = p + b2s;
        float other = SWZ(ov, 0x401F);                // xor-16: r1 <-> r2
        float r1v = net ? other : ov;                 // = r1 * Castd
        float r2v = net ? ov : other;                 // = r2 * Cbstd

        // physics
        v2f   Cab_p = pkfma(xab, STD2, MEAN2);
        float Cc_p  = fmaf(xc, Cbstd, Cbmean);
        float dCa   = fmaf(-0.1f, Cab_p.x, fCaf) - r1v;
        float dCb   = fmaf(-0.1f, Cab_p.y, fmaf(-3.0f, r2v, r1v));
        float dCc   = fmaf(-0.1f, Cc_p, r2v);
        v2f d; d.x = dCa; d.y = dCb;
        kab = d * ISTD2;                              // pk_mul
        kc  = dCc * invCbstd;
    };

    const auto R = std::integral_constant<bool, false>{};
    const auto X = std::integral_constant<bool, true>{};

    for (int t = 0; t < T_STEPS; ++t) {
        float v = selA ? Cab.x : (selB ? Cab.y : Cc);
        if (active) { *sp = v; sp += sstr; }
        if (t == T_STEPS - 1) break;

        float utn  = ldf(u_, ubase + t + 1, vU);
        float fCaf = 0.1f * fmaf(ut, us, um);

        v2f k1ab, k2ab, k3ab, k4ab;
        float k1c, k2c, k3c, k4c;

        fxu(R, Cab, Cc, fCaf, k1ab, k1c);
        fxu(X, pkfma(HALF2, k1ab, Cab), fmaf(0.5f, k1c, Cc), fCaf, k2ab, k2c);
        fxu(R, pkfma(HALF2, k2ab, Cab), fmaf(0.5f, k2c, Cc), fCaf, k3ab, k3c);
        fxu(X, Cab + k3ab, Cc + k3c, fCaf, k4ab, k4c);

        v2f   sab = pkfma(TWO2, k2ab + k3ab, k1ab) + k4ab;
        float sc  = fmaf(2.0f, k2c + k3c, k1c) + k4c;
        Cab = pkfma(SIXTH2, sab, Cab);
        Cc  = fmaf(1.0f / 6.0f, sc, Cc);
        ut  = utn;
    }
}

extern "C" void kernel_launch(void* const* d_in, const int* in_sizes, int n_in,
                              void* d_out, int out_size, void* d_ws, size_t ws_size,
                              hipStream_t stream) {
    (void)in_sizes; (void)n_in; (void)out_size; (void)d_ws; (void)ws_size;
    dim3 grid(B_SEQ / 2);
    dim3 block(64);
    reac_rk4_kernel<<<grid, block, 0, stream>>>(
        d_in[0],  d_in[1],
        d_in[2],  d_in[3],  d_in[4],  d_in[5],  d_in[6],  d_in[7],
        d_in[8],  d_in[9],  d_in[10], d_in[11], d_in[12], d_in[13],
        d_in[14], d_in[15], d_in[16], d_in[17],
        (float*)d_out);
}